// Round 1
// baseline (236.562 us; speedup 1.0000x reference)
//
#include <hip/hip_runtime.h>
#include <hip/hip_bf16.h>

// Problem constants (fixed by setup_inputs)
#define NB    16          // clouds
#define NC    1024        // coarse points per cloud
#define NF    4096        // fine points per cloud
#define NFINE (NB*NF)     // 65536
#define CIN   256
#define CSKIP 128
#define KH    (CIN+CSKIP) // 384
#define CMID  256
#define COUT  256

typedef __attribute__((ext_vector_type(8))) short short8;
typedef __attribute__((ext_vector_type(4))) float f32x4;

// ---------------- K1: 3-NN + inverse-distance weights ----------------
__global__ __launch_bounds__(256)
void knn_kernel(const float* __restrict__ pos,       // [NB*NC][3]
                const float* __restrict__ pos_skip,  // [NFINE][3]
                int* __restrict__ widx,              // [NFINE*3] global rows
                float* __restrict__ wval)            // [NFINE*3] normalized
{
    __shared__ float sp[NC*3];
    const int blocks_per_cloud = NF/256;             // 16
    const int b  = blockIdx.x / blocks_per_cloud;
    const int qb = blockIdx.x % blocks_per_cloud;
    const float* pc = pos + (size_t)b*NC*3;
    for (int i = threadIdx.x; i < NC*3; i += 256) sp[i] = pc[i];
    __syncthreads();

    const int q = b*NF + qb*256 + threadIdx.x;
    const float qx = pos_skip[(size_t)q*3+0];
    const float qy = pos_skip[(size_t)q*3+1];
    const float qz = pos_skip[(size_t)q*3+2];

    float d0 = 3.0e38f, dA = 3.0e38f, dB = 3.0e38f;
    int   i0 = 0,       iA = 0,       iB = 0;
    for (int j = 0; j < NC; ++j) {
        float dx = qx - sp[3*j+0];
        float dy = qy - sp[3*j+1];
        float dz = qz - sp[3*j+2];
        float d = dx*dx + dy*dy + dz*dz;
        if (d < dB) {
            if (d < dA) {
                dB = dA; iB = iA;
                if (d < d0) { dA = d0; iA = i0; d0 = d; i0 = j; }
                else        { dA = d;  iA = j; }
            } else { dB = d; iB = j; }
        }
    }
    float w0 = 1.0f / fmaxf(d0, 1e-16f);
    float w1 = 1.0f / fmaxf(dA, 1e-16f);
    float w2 = 1.0f / fmaxf(dB, 1e-16f);
    float inv = 1.0f / (w0 + w1 + w2);
    widx[q*3+0] = b*NC + i0;  wval[q*3+0] = w0*inv;
    widx[q*3+1] = b*NC + iA;  wval[q*3+1] = w1*inv;
    widx[q*3+2] = b*NC + iB;  wval[q*3+2] = w2*inv;
}

// ---------------- K2: weights -> bf16, transposed [N][K] ----------------
__global__ __launch_bounds__(256)
void prep_weights(const float* __restrict__ W1, const float* __restrict__ W2,
                  __hip_bfloat16* __restrict__ W1t, __hip_bfloat16* __restrict__ W2t)
{
    int e = blockIdx.x*256 + threadIdx.x;
    if (e < CMID*KH) {                       // W1t[n][k] = W1[k][n]
        int n = e / KH, k = e % KH;
        W1t[e] = __float2bfloat16(W1[(size_t)k*CMID + n]);
    }
    int e2 = e - CMID*KH;
    if (e2 >= 0 && e2 < COUT*CMID) {         // W2t[n][k] = W2[k][n]
        int n = e2 / CMID, k = e2 % CMID;
        W2t[e2] = __float2bfloat16(W2[(size_t)k*COUT + n]);
    }
}

// ---------------- K3: interpolate + concat -> h bf16 [NFINE][384] ----------------
__global__ __launch_bounds__(256)
void build_h_kernel(const float* __restrict__ x,       // [NB*NC][CIN]
                    const float* __restrict__ x_skip,  // [NFINE][CSKIP]
                    const int* __restrict__ widx,
                    const float* __restrict__ wval,
                    __hip_bfloat16* __restrict__ h)    // [NFINE][KH]
{
    size_t e = (size_t)blockIdx.x*256 + threadIdx.x;
    if (e >= (size_t)NFINE*KH) return;
    int row = (int)(e / KH);
    int c   = (int)(e % KH);
    float v;
    if (c < CIN) {
        int ba = row*3;
        int j0 = widx[ba+0], j1 = widx[ba+1], j2 = widx[ba+2];
        float w0 = wval[ba+0], w1 = wval[ba+1], w2 = wval[ba+2];
        v = w0*x[(size_t)j0*CIN + c] + w1*x[(size_t)j1*CIN + c] + w2*x[(size_t)j2*CIN + c];
    } else {
        v = x_skip[(size_t)row*CSKIP + (c - CIN)];
    }
    h[e] = __float2bfloat16(v);
}

// ---------------- K4/K5: GEMM (M x K)·(K x N=256 via Bt[N][K]) + bias + relu ----------------
// tile 128x64, 4 waves, each wave 32 rows x 64 cols, mfma 16x16x32 bf16
template<int K, bool STORE_BF16>
__global__ __launch_bounds__(256)
void gemm_bias_relu(const __hip_bfloat16* __restrict__ A,   // [M][K] bf16
                    const __hip_bfloat16* __restrict__ Bt,  // [N][K] bf16
                    const float* __restrict__ bias,         // [N]
                    __hip_bfloat16* __restrict__ outb,      // [M][256] if STORE_BF16
                    float* __restrict__ outf)               // [M][256] else
{
    __shared__ __align__(16) short As[128][40];  // +8 pad: rows land on 8 distinct bank groups
    __shared__ __align__(16) short Bs[64][40];
    const int m0 = blockIdx.x * 128;
    const int n0 = blockIdx.y * 64;
    const int t = threadIdx.x;
    const int wave = t >> 6, lane = t & 63;
    const short* Ar = (const short*)A;
    const short* Br = (const short*)Bt;

    f32x4 acc[2][4] = {};

    for (int k0 = 0; k0 < K; k0 += 32) {
        __syncthreads();
        // stage A tile: 128 rows x 32 cols = 512 chunks of 8 bf16 (16B)
        {
            int ch = t, row = ch >> 2, cc = ch & 3;
            *(uint4*)&As[row][cc*8] = *(const uint4*)&Ar[(size_t)(m0+row)*K + k0 + cc*8];
            ch = t + 256; row = ch >> 2; cc = ch & 3;
            *(uint4*)&As[row][cc*8] = *(const uint4*)&Ar[(size_t)(m0+row)*K + k0 + cc*8];
            row = t >> 2; cc = t & 3;
            *(uint4*)&Bs[row][cc*8] = *(const uint4*)&Br[(size_t)(n0+row)*K + k0 + cc*8];
        }
        __syncthreads();

        const int kf = (lane >> 4) * 8;   // k-offset of this lane's fragment
        const int rl = lane & 15;
        short8 a0 = *(const short8*)&As[wave*32 +  0 + rl][kf];
        short8 a1 = *(const short8*)&As[wave*32 + 16 + rl][kf];
        short8 b0 = *(const short8*)&Bs[ 0 + rl][kf];
        short8 b1 = *(const short8*)&Bs[16 + rl][kf];
        short8 b2 = *(const short8*)&Bs[32 + rl][kf];
        short8 b3 = *(const short8*)&Bs[48 + rl][kf];
        acc[0][0] = __builtin_amdgcn_mfma_f32_16x16x32_bf16(a0, b0, acc[0][0], 0,0,0);
        acc[0][1] = __builtin_amdgcn_mfma_f32_16x16x32_bf16(a0, b1, acc[0][1], 0,0,0);
        acc[0][2] = __builtin_amdgcn_mfma_f32_16x16x32_bf16(a0, b2, acc[0][2], 0,0,0);
        acc[0][3] = __builtin_amdgcn_mfma_f32_16x16x32_bf16(a0, b3, acc[0][3], 0,0,0);
        acc[1][0] = __builtin_amdgcn_mfma_f32_16x16x32_bf16(a1, b0, acc[1][0], 0,0,0);
        acc[1][1] = __builtin_amdgcn_mfma_f32_16x16x32_bf16(a1, b1, acc[1][1], 0,0,0);
        acc[1][2] = __builtin_amdgcn_mfma_f32_16x16x32_bf16(a1, b2, acc[1][2], 0,0,0);
        acc[1][3] = __builtin_amdgcn_mfma_f32_16x16x32_bf16(a1, b3, acc[1][3], 0,0,0);
    }

    // epilogue: D layout col=lane&15, row=(lane>>4)*4+i  [guide §3, m89-verified]
    #pragma unroll
    for (int mr = 0; mr < 2; ++mr)
    #pragma unroll
    for (int nc = 0; nc < 4; ++nc) {
        const int col = n0 + nc*16 + (lane & 15);
        const float bv = bias[col];
        #pragma unroll
        for (int i = 0; i < 4; ++i) {
            const int row = m0 + wave*32 + mr*16 + (lane >> 4)*4 + i;
            float v = acc[mr][nc][i] + bv;
            v = fmaxf(v, 0.0f);
            if (STORE_BF16) outb[(size_t)row*256 + col] = __float2bfloat16(v);
            else            outf[(size_t)row*256 + col] = v;
        }
    }
}

// ---------------- K6: pos_skip + batch chunks ----------------
__global__ __launch_bounds__(256)
void tail_kernel(const float* __restrict__ pos_skip, float* __restrict__ out)
{
    int e = blockIdx.x*256 + threadIdx.x;
    if (e < NFINE*3) out[(size_t)NFINE*COUT + e] = pos_skip[e];
    if (e < NFINE)   out[(size_t)NFINE*COUT + (size_t)NFINE*3 + e] = (float)(e / NF);
}

extern "C" void kernel_launch(void* const* d_in, const int* in_sizes, int n_in,
                              void* d_out, int out_size, void* d_ws, size_t ws_size,
                              hipStream_t stream) {
    const float* x        = (const float*)d_in[0];
    const float* pos      = (const float*)d_in[1];
    const float* x_skip   = (const float*)d_in[4];
    const float* pos_skip = (const float*)d_in[5];
    const float* W1       = (const float*)d_in[8];
    const float* b1       = (const float*)d_in[9];
    const float* W2       = (const float*)d_in[10];
    const float* b2       = (const float*)d_in[11];
    float* out = (float*)d_out;
    char* ws = (char*)d_ws;

    // workspace layout (all 16B-aligned)
    int*            widx = (int*)  (ws + 0);          //   786,432 B
    float*          wval = (float*)(ws + 786432);     //   786,432 B
    __hip_bfloat16* W1t  = (__hip_bfloat16*)(ws + 1572864);  // 196,608 B
    __hip_bfloat16* W2t  = (__hip_bfloat16*)(ws + 1769472);  // 131,072 B
    __hip_bfloat16* h    = (__hip_bfloat16*)(ws + 1900544);  // 50,331,648 B
    __hip_bfloat16* h1   = (__hip_bfloat16*)(ws + 52232192); // 33,554,432 B
    // total 85,786,624 B

    hipLaunchKernelGGL(knn_kernel, dim3(NB*(NF/256)), dim3(256), 0, stream,
                       pos, pos_skip, widx, wval);
    hipLaunchKernelGGL(prep_weights, dim3((CMID*KH + COUT*CMID + 255)/256), dim3(256), 0, stream,
                       W1, W2, W1t, W2t);
    hipLaunchKernelGGL(build_h_kernel, dim3((NFINE*KH)/256), dim3(256), 0, stream,
                       x, x_skip, widx, wval, h);
    hipLaunchKernelGGL((gemm_bias_relu<KH, true>), dim3(NFINE/128, CMID/64), dim3(256), 0, stream,
                       h, W1t, b1, h1, nullptr);
    hipLaunchKernelGGL((gemm_bias_relu<CMID, false>), dim3(NFINE/128, COUT/64), dim3(256), 0, stream,
                       h1, W2t, b2, nullptr, out);
    hipLaunchKernelGGL(tail_kernel, dim3((NFINE*3 + 255)/256), dim3(256), 0, stream,
                       pos_skip, out);
}

// Round 2
// 159.268 us; speedup vs baseline: 1.4853x; 1.4853x over previous
//
#include <hip/hip_runtime.h>
#include <hip/hip_bf16.h>

// Problem constants (fixed by setup_inputs)
#define NB    16          // clouds
#define NC    1024        // coarse points per cloud
#define NF    4096        // fine points per cloud
#define NFINE (NB*NF)     // 65536
#define CIN   256
#define CSKIP 128
#define KH    (CIN+CSKIP) // 384
#define CMID  256
#define COUT  256

typedef __attribute__((ext_vector_type(8))) short short8;
typedef __attribute__((ext_vector_type(4))) float f32x4;

// ---------------- K1: 3-NN + inverse-distance weights ----------------
// 8 lanes per query: each scans 128 candidates (register top-3), then merges
// sorted triples across the 8-lane group via shfl_xor. 2048 blocks -> 32 waves/CU.
#define KNN_G   8
#define KNN_QPB (256/KNN_G)   // 32 queries per block

__global__ __launch_bounds__(256)
void knn_kernel(const float* __restrict__ pos,       // [NB*NC][3]
                const float* __restrict__ pos_skip,  // [NFINE][3]
                int* __restrict__ widx,              // [NFINE*3] global rows
                float* __restrict__ wval)            // [NFINE*3] normalized
{
    __shared__ float sp[NC*3];
    const int blocks_per_cloud = NF/KNN_QPB;         // 128
    const int b  = blockIdx.x / blocks_per_cloud;
    const int qb = blockIdx.x % blocks_per_cloud;
    const float* pc = pos + (size_t)b*NC*3;
    for (int i = threadIdx.x; i < NC*3; i += 256) sp[i] = pc[i];
    __syncthreads();

    const int t  = threadIdx.x;
    const int g  = t & (KNN_G-1);     // candidate lane within group
    const int ql = t >> 3;            // query slot in block (0..31)
    const int q  = b*NF + qb*KNN_QPB + ql;
    const float qx = pos_skip[(size_t)q*3+0];
    const float qy = pos_skip[(size_t)q*3+1];
    const float qz = pos_skip[(size_t)q*3+2];

    float d0 = 3.0e38f, dA = 3.0e38f, dB = 3.0e38f;
    int   i0 = 0,       iA = 0,       iB = 0;

    #pragma unroll 4
    for (int j = g; j < NC; j += KNN_G) {
        float dx = qx - sp[3*j+0];
        float dy = qy - sp[3*j+1];
        float dz = qz - sp[3*j+2];
        float d = dx*dx + dy*dy + dz*dz;
        if (d < dB) {
            if (d < dA) {
                dB = dA; iB = iA;
                if (d < d0) { dA = d0; iA = i0; d0 = d; i0 = j; }
                else        { dA = d;  iA = j; }
            } else { dB = d; iB = j; }
        }
    }

    // merge top-3 across the 8-lane group (lanes are consecutive, so
    // shfl_xor with mask<8 stays within the group)
    #pragma unroll
    for (int m = 1; m < KNN_G; m <<= 1) {
        float e0 = __shfl_xor(d0, m), e1 = __shfl_xor(dA, m), e2 = __shfl_xor(dB, m);
        int   f0 = __shfl_xor(i0, m), f1 = __shfl_xor(iA, m), f2 = __shfl_xor(iB, m);
        // insert e0,e1,e2 (sorted) into (d0<=dA<=dB)
        float d; int j;
        d = e0; j = f0;
        if (d < dB) { if (d < dA) { dB=dA; iB=iA; if (d < d0) { dA=d0; iA=i0; d0=d; i0=j; } else { dA=d; iA=j; } } else { dB=d; iB=j; } }
        d = e1; j = f1;
        if (d < dB) { if (d < dA) { dB=dA; iB=iA; if (d < d0) { dA=d0; iA=i0; d0=d; i0=j; } else { dA=d; iA=j; } } else { dB=d; iB=j; } }
        d = e2; j = f2;
        if (d < dB) { if (d < dA) { dB=dA; iB=iA; if (d < d0) { dA=d0; iA=i0; d0=d; i0=j; } else { dA=d; iA=j; } } else { dB=d; iB=j; } }
    }

    if (g == 0) {
        float w0 = 1.0f / fmaxf(d0, 1e-16f);
        float w1 = 1.0f / fmaxf(dA, 1e-16f);
        float w2 = 1.0f / fmaxf(dB, 1e-16f);
        float inv = 1.0f / (w0 + w1 + w2);
        widx[q*3+0] = b*NC + i0;  wval[q*3+0] = w0*inv;
        widx[q*3+1] = b*NC + iA;  wval[q*3+1] = w1*inv;
        widx[q*3+2] = b*NC + iB;  wval[q*3+2] = w2*inv;
    }
}

// ---------------- K2: weights -> bf16, transposed [N][K] ----------------
__global__ __launch_bounds__(256)
void prep_weights(const float* __restrict__ W1, const float* __restrict__ W2,
                  __hip_bfloat16* __restrict__ W1t, __hip_bfloat16* __restrict__ W2t)
{
    int e = blockIdx.x*256 + threadIdx.x;
    if (e < CMID*KH) {                       // W1t[n][k] = W1[k][n]
        int n = e / KH, k = e % KH;
        W1t[e] = __float2bfloat16(W1[(size_t)k*CMID + n]);
    }
    int e2 = e - CMID*KH;
    if (e2 >= 0 && e2 < COUT*CMID) {         // W2t[n][k] = W2[k][n]
        int n = e2 / CMID, k = e2 % CMID;
        W2t[e2] = __float2bfloat16(W2[(size_t)k*COUT + n]);
    }
}

// ---------------- K3: interpolate + concat -> h bf16 [NFINE][384] ----------------
__global__ __launch_bounds__(256)
void build_h_kernel(const float* __restrict__ x,       // [NB*NC][CIN]
                    const float* __restrict__ x_skip,  // [NFINE][CSKIP]
                    const int* __restrict__ widx,
                    const float* __restrict__ wval,
                    __hip_bfloat16* __restrict__ h)    // [NFINE][KH]
{
    size_t e = (size_t)blockIdx.x*256 + threadIdx.x;
    if (e >= (size_t)NFINE*KH) return;
    int row = (int)(e / KH);
    int c   = (int)(e % KH);
    float v;
    if (c < CIN) {
        int ba = row*3;
        int j0 = widx[ba+0], j1 = widx[ba+1], j2 = widx[ba+2];
        float w0 = wval[ba+0], w1 = wval[ba+1], w2 = wval[ba+2];
        v = w0*x[(size_t)j0*CIN + c] + w1*x[(size_t)j1*CIN + c] + w2*x[(size_t)j2*CIN + c];
    } else {
        v = x_skip[(size_t)row*CSKIP + (c - CIN)];
    }
    h[e] = __float2bfloat16(v);
}

// ---------------- K4/K5: GEMM (M x K)·(K x N=256 via Bt[N][K]) + bias + relu ----------------
// tile 128x64, 4 waves, each wave 32 rows x 64 cols, mfma 16x16x32 bf16
template<int K, bool STORE_BF16>
__global__ __launch_bounds__(256)
void gemm_bias_relu(const __hip_bfloat16* __restrict__ A,   // [M][K] bf16
                    const __hip_bfloat16* __restrict__ Bt,  // [N][K] bf16
                    const float* __restrict__ bias,         // [N]
                    __hip_bfloat16* __restrict__ outb,      // [M][256] if STORE_BF16
                    float* __restrict__ outf)               // [M][256] else
{
    __shared__ __align__(16) short As[128][40];  // +8 pad: rows land on 8 distinct bank groups
    __shared__ __align__(16) short Bs[64][40];
    const int m0 = blockIdx.x * 128;
    const int n0 = blockIdx.y * 64;
    const int t = threadIdx.x;
    const int wave = t >> 6, lane = t & 63;
    const short* Ar = (const short*)A;
    const short* Br = (const short*)Bt;

    f32x4 acc[2][4] = {};

    for (int k0 = 0; k0 < K; k0 += 32) {
        __syncthreads();
        // stage A tile: 128 rows x 32 cols = 512 chunks of 8 bf16 (16B)
        {
            int ch = t, row = ch >> 2, cc = ch & 3;
            *(uint4*)&As[row][cc*8] = *(const uint4*)&Ar[(size_t)(m0+row)*K + k0 + cc*8];
            ch = t + 256; row = ch >> 2; cc = ch & 3;
            *(uint4*)&As[row][cc*8] = *(const uint4*)&Ar[(size_t)(m0+row)*K + k0 + cc*8];
            row = t >> 2; cc = t & 3;
            *(uint4*)&Bs[row][cc*8] = *(const uint4*)&Br[(size_t)(n0+row)*K + k0 + cc*8];
        }
        __syncthreads();

        const int kf = (lane >> 4) * 8;   // k-offset of this lane's fragment
        const int rl = lane & 15;
        short8 a0 = *(const short8*)&As[wave*32 +  0 + rl][kf];
        short8 a1 = *(const short8*)&As[wave*32 + 16 + rl][kf];
        short8 b0 = *(const short8*)&Bs[ 0 + rl][kf];
        short8 b1 = *(const short8*)&Bs[16 + rl][kf];
        short8 b2 = *(const short8*)&Bs[32 + rl][kf];
        short8 b3 = *(const short8*)&Bs[48 + rl][kf];
        acc[0][0] = __builtin_amdgcn_mfma_f32_16x16x32_bf16(a0, b0, acc[0][0], 0,0,0);
        acc[0][1] = __builtin_amdgcn_mfma_f32_16x16x32_bf16(a0, b1, acc[0][1], 0,0,0);
        acc[0][2] = __builtin_amdgcn_mfma_f32_16x16x32_bf16(a0, b2, acc[0][2], 0,0,0);
        acc[0][3] = __builtin_amdgcn_mfma_f32_16x16x32_bf16(a0, b3, acc[0][3], 0,0,0);
        acc[1][0] = __builtin_amdgcn_mfma_f32_16x16x32_bf16(a1, b0, acc[1][0], 0,0,0);
        acc[1][1] = __builtin_amdgcn_mfma_f32_16x16x32_bf16(a1, b1, acc[1][1], 0,0,0);
        acc[1][2] = __builtin_amdgcn_mfma_f32_16x16x32_bf16(a1, b2, acc[1][2], 0,0,0);
        acc[1][3] = __builtin_amdgcn_mfma_f32_16x16x32_bf16(a1, b3, acc[1][3], 0,0,0);
    }

    // epilogue: D layout col=lane&15, row=(lane>>4)*4+i  [guide §3, m89-verified]
    #pragma unroll
    for (int mr = 0; mr < 2; ++mr)
    #pragma unroll
    for (int nc = 0; nc < 4; ++nc) {
        const int col = n0 + nc*16 + (lane & 15);
        const float bv = bias[col];
        #pragma unroll
        for (int i = 0; i < 4; ++i) {
            const int row = m0 + wave*32 + mr*16 + (lane >> 4)*4 + i;
            float v = acc[mr][nc][i] + bv;
            v = fmaxf(v, 0.0f);
            if (STORE_BF16) outb[(size_t)row*256 + col] = __float2bfloat16(v);
            else            outf[(size_t)row*256 + col] = v;
        }
    }
}

// ---------------- K6: pos_skip + batch chunks ----------------
__global__ __launch_bounds__(256)
void tail_kernel(const float* __restrict__ pos_skip, float* __restrict__ out)
{
    int e = blockIdx.x*256 + threadIdx.x;
    if (e < NFINE*3) out[(size_t)NFINE*COUT + e] = pos_skip[e];
    if (e < NFINE)   out[(size_t)NFINE*COUT + (size_t)NFINE*3 + e] = (float)(e / NF);
}

extern "C" void kernel_launch(void* const* d_in, const int* in_sizes, int n_in,
                              void* d_out, int out_size, void* d_ws, size_t ws_size,
                              hipStream_t stream) {
    const float* x        = (const float*)d_in[0];
    const float* pos      = (const float*)d_in[1];
    const float* x_skip   = (const float*)d_in[4];
    const float* pos_skip = (const float*)d_in[5];
    const float* W1       = (const float*)d_in[8];
    const float* b1       = (const float*)d_in[9];
    const float* W2       = (const float*)d_in[10];
    const float* b2       = (const float*)d_in[11];
    float* out = (float*)d_out;
    char* ws = (char*)d_ws;

    // workspace layout (all 16B-aligned)
    int*            widx = (int*)  (ws + 0);          //   786,432 B
    float*          wval = (float*)(ws + 786432);     //   786,432 B
    __hip_bfloat16* W1t  = (__hip_bfloat16*)(ws + 1572864);  // 196,608 B
    __hip_bfloat16* W2t  = (__hip_bfloat16*)(ws + 1769472);  // 131,072 B
    __hip_bfloat16* h    = (__hip_bfloat16*)(ws + 1900544);  // 50,331,648 B
    __hip_bfloat16* h1   = (__hip_bfloat16*)(ws + 52232192); // 33,554,432 B
    // total 85,786,624 B

    hipLaunchKernelGGL(knn_kernel, dim3(NB*(NF/KNN_QPB)), dim3(256), 0, stream,
                       pos, pos_skip, widx, wval);
    hipLaunchKernelGGL(prep_weights, dim3((CMID*KH + COUT*CMID + 255)/256), dim3(256), 0, stream,
                       W1, W2, W1t, W2t);
    hipLaunchKernelGGL(build_h_kernel, dim3((NFINE*KH)/256), dim3(256), 0, stream,
                       x, x_skip, widx, wval, h);
    hipLaunchKernelGGL((gemm_bias_relu<KH, true>), dim3(NFINE/128, CMID/64), dim3(256), 0, stream,
                       h, W1t, b1, h1, nullptr);
    hipLaunchKernelGGL((gemm_bias_relu<CMID, false>), dim3(NFINE/128, COUT/64), dim3(256), 0, stream,
                       h1, W2t, b2, nullptr, out);
    hipLaunchKernelGGL(tail_kernel, dim3((NFINE*3 + 255)/256), dim3(256), 0, stream,
                       pos_skip, out);
}

// Round 3
// 106.105 us; speedup vs baseline: 2.2295x; 1.5010x over previous
//
#include <hip/hip_runtime.h>
#include <hip/hip_bf16.h>

// Problem constants (fixed by setup_inputs)
#define NB    16          // clouds
#define NC    1024        // coarse points per cloud
#define NF    4096        // fine points per cloud
#define NFINE (NB*NF)     // 65536
#define CIN   256
#define CSKIP 128
#define KH    (CIN+CSKIP) // 384
#define CMID  256
#define COUT  256

typedef __attribute__((ext_vector_type(8))) short short8;
typedef __attribute__((ext_vector_type(4))) float f32x4;

// ---------------- K1: 3-NN + inverse-distance weights ----------------
// 8 lanes per query, register top-3, shfl_xor merge. 2048 blocks.
#define KNN_G   8
#define KNN_QPB (256/KNN_G)   // 32 queries per block

__global__ __launch_bounds__(256)
void knn_kernel(const float* __restrict__ pos,
                const float* __restrict__ pos_skip,
                int* __restrict__ widx,
                float* __restrict__ wval)
{
    __shared__ float sp[NC*3];
    const int blocks_per_cloud = NF/KNN_QPB;         // 128
    const int b  = blockIdx.x / blocks_per_cloud;
    const int qb = blockIdx.x % blocks_per_cloud;
    const float* pc = pos + (size_t)b*NC*3;
    for (int i = threadIdx.x; i < NC*3; i += 256) sp[i] = pc[i];
    __syncthreads();

    const int t  = threadIdx.x;
    const int g  = t & (KNN_G-1);
    const int ql = t >> 3;
    const int q  = b*NF + qb*KNN_QPB + ql;
    const float qx = pos_skip[(size_t)q*3+0];
    const float qy = pos_skip[(size_t)q*3+1];
    const float qz = pos_skip[(size_t)q*3+2];

    float d0 = 3.0e38f, dA = 3.0e38f, dB = 3.0e38f;
    int   i0 = 0,       iA = 0,       iB = 0;

    #pragma unroll 4
    for (int j = g; j < NC; j += KNN_G) {
        float dx = qx - sp[3*j+0];
        float dy = qy - sp[3*j+1];
        float dz = qz - sp[3*j+2];
        float d = dx*dx + dy*dy + dz*dz;
        if (d < dB) {
            if (d < dA) {
                dB = dA; iB = iA;
                if (d < d0) { dA = d0; iA = i0; d0 = d; i0 = j; }
                else        { dA = d;  iA = j; }
            } else { dB = d; iB = j; }
        }
    }

    #pragma unroll
    for (int m = 1; m < KNN_G; m <<= 1) {
        float e0 = __shfl_xor(d0, m), e1 = __shfl_xor(dA, m), e2 = __shfl_xor(dB, m);
        int   f0 = __shfl_xor(i0, m), f1 = __shfl_xor(iA, m), f2 = __shfl_xor(iB, m);
        float d; int j;
        d = e0; j = f0;
        if (d < dB) { if (d < dA) { dB=dA; iB=iA; if (d < d0) { dA=d0; iA=i0; d0=d; i0=j; } else { dA=d; iA=j; } } else { dB=d; iB=j; } }
        d = e1; j = f1;
        if (d < dB) { if (d < dA) { dB=dA; iB=iA; if (d < d0) { dA=d0; iA=i0; d0=d; i0=j; } else { dA=d; iA=j; } } else { dB=d; iB=j; } }
        d = e2; j = f2;
        if (d < dB) { if (d < dA) { dB=dA; iB=iA; if (d < d0) { dA=d0; iA=i0; d0=d; i0=j; } else { dA=d; iA=j; } } else { dB=d; iB=j; } }
    }

    if (g == 0) {
        float w0 = 1.0f / fmaxf(d0, 1e-16f);
        float w1 = 1.0f / fmaxf(dA, 1e-16f);
        float w2 = 1.0f / fmaxf(dB, 1e-16f);
        float inv = 1.0f / (w0 + w1 + w2);
        widx[q*3+0] = b*NC + i0;  wval[q*3+0] = w0*inv;
        widx[q*3+1] = b*NC + iA;  wval[q*3+1] = w1*inv;
        widx[q*3+2] = b*NC + iB;  wval[q*3+2] = w2*inv;
    }
}

// ---------------- K2: weights -> bf16, transposed [N][K] ----------------
__global__ __launch_bounds__(256)
void prep_weights(const float* __restrict__ W1, const float* __restrict__ W2,
                  __hip_bfloat16* __restrict__ W1t, __hip_bfloat16* __restrict__ W2t)
{
    int e = blockIdx.x*256 + threadIdx.x;
    if (e < CMID*KH) {                       // W1t[n][k] = W1[k][n]
        int n = e / KH, k = e % KH;
        W1t[e] = __float2bfloat16(W1[(size_t)k*CMID + n]);
    }
    int e2 = e - CMID*KH;
    if (e2 >= 0 && e2 < COUT*CMID) {         // W2t[n][k] = W2[k][n]
        int n = e2 / CMID, k = e2 % CMID;
        W2t[e2] = __float2bfloat16(W2[(size_t)k*COUT + n]);
    }
}

// ---------------- fused GEMM: tile 64x256, 8 waves (2x4), mfma 16x16x32 ----------------
// MODE 1: A built on the fly = [interp(x) | x_skip] (KTOT=384), store bf16 h1
// MODE 0: A = bf16 matrix (KTOT=256), store f32 + bias + relu
#define BM  64
#define BN  256
#define BK  64
#define LDK (BK+8)   // +8 shorts pad: conflict-free frag reads (verified 0 conflicts r1)

template<int MODE, int KTOT>
__global__ __launch_bounds__(512, 4)
void gemm_fused(const void* __restrict__ Asrc,        // MODE1: x fp32 [NB*NC][CIN]; MODE0: bf16 [M][KTOT]
                const float* __restrict__ x_skip,     // MODE1 only
                const int* __restrict__ widx,
                const float* __restrict__ wval,
                const __hip_bfloat16* __restrict__ Bt, // [BN][KTOT]
                const float* __restrict__ bias,        // [BN]
                __hip_bfloat16* __restrict__ outb,     // MODE1
                float* __restrict__ outf)              // MODE0
{
    __shared__ __align__(16) short As[BM][LDK];
    __shared__ __align__(16) short Bs[BN][LDK];
    const int m0 = blockIdx.x * BM;
    const int t = threadIdx.x;
    const int wave = t >> 6, lane = t & 63;
    const int wm = wave >> 2, wn = wave & 3;   // 2 x 4 wave grid
    const short* Br = (const short*)Bt;

    // this thread's fixed A-staging slot: row ar, col chunk acc8
    const int ar   = t >> 3;        // 0..63
    const int ac8  = (t & 7) * 8;   // 0..56

    int j0=0, j1=0, j2=0; float w0=0.f, w1=0.f, w2=0.f;
    if (MODE == 1) {
        const int gr = m0 + ar;
        j0 = widx[gr*3+0]; j1 = widx[gr*3+1]; j2 = widx[gr*3+2];
        w0 = wval[gr*3+0]; w1 = wval[gr*3+1]; w2 = wval[gr*3+2];
    }

    f32x4 acc[2][4] = {};   // 8 frags = 32 VGPR

    for (int k0 = 0; k0 < KTOT; k0 += BK) {
        __syncthreads();
        // ---- stage A (one 8-elem chunk per thread) ----
        if (MODE == 0) {
            const short* Ar = (const short*)Asrc;
            *(uint4*)&As[ar][ac8] = *(const uint4*)&Ar[(size_t)(m0+ar)*KTOT + k0 + ac8];
        } else {
            const int k = k0 + ac8;
            float v[8];
            if (k < CIN) {
                const float* xp = (const float*)Asrc;
                const float* p0 = &xp[(size_t)j0*CIN + k];
                const float* p1 = &xp[(size_t)j1*CIN + k];
                const float* p2 = &xp[(size_t)j2*CIN + k];
                float4 a0 = *(const float4*)p0, a1 = *(const float4*)(p0+4);
                float4 b0 = *(const float4*)p1, b1 = *(const float4*)(p1+4);
                float4 c0 = *(const float4*)p2, c1 = *(const float4*)(p2+4);
                v[0] = w0*a0.x + w1*b0.x + w2*c0.x;
                v[1] = w0*a0.y + w1*b0.y + w2*c0.y;
                v[2] = w0*a0.z + w1*b0.z + w2*c0.z;
                v[3] = w0*a0.w + w1*b0.w + w2*c0.w;
                v[4] = w0*a1.x + w1*b1.x + w2*c1.x;
                v[5] = w0*a1.y + w1*b1.y + w2*c1.y;
                v[6] = w0*a1.z + w1*b1.z + w2*c1.z;
                v[7] = w0*a1.w + w1*b1.w + w2*c1.w;
            } else {
                const float* sp = &x_skip[(size_t)(m0+ar)*CSKIP + (k - CIN)];
                float4 s0 = *(const float4*)sp, s1 = *(const float4*)(sp+4);
                v[0]=s0.x; v[1]=s0.y; v[2]=s0.z; v[3]=s0.w;
                v[4]=s1.x; v[5]=s1.y; v[6]=s1.z; v[7]=s1.w;
            }
            short8 sv;
            #pragma unroll
            for (int i = 0; i < 8; ++i) {
                __hip_bfloat16 bb = __float2bfloat16(v[i]);
                ((short*)&sv)[i] = *(short*)&bb;
            }
            *(short8*)&As[ar][ac8] = sv;
        }
        // ---- stage B (4 chunks per thread: 256 rows x 64 cols) ----
        #pragma unroll
        for (int i = 0; i < 4; ++i) {
            const int ch = t + i*512;
            const int n = ch >> 3, cc = (ch & 7) * 8;
            *(uint4*)&Bs[n][cc] = *(const uint4*)&Br[(size_t)n*KTOT + k0 + cc];
        }
        __syncthreads();

        // ---- MFMA: wave computes rows wm*32..+32, cols wn*64..+64 ----
        #pragma unroll
        for (int kk = 0; kk < BK; kk += 32) {
            const int kf = kk + (lane >> 4) * 8;
            const int rl = lane & 15;
            short8 a0 = *(const short8*)&As[wm*32 +  0 + rl][kf];
            short8 a1 = *(const short8*)&As[wm*32 + 16 + rl][kf];
            short8 b0 = *(const short8*)&Bs[wn*64 +  0 + rl][kf];
            short8 b1 = *(const short8*)&Bs[wn*64 + 16 + rl][kf];
            short8 b2 = *(const short8*)&Bs[wn*64 + 32 + rl][kf];
            short8 b3 = *(const short8*)&Bs[wn*64 + 48 + rl][kf];
            acc[0][0] = __builtin_amdgcn_mfma_f32_16x16x32_bf16(a0, b0, acc[0][0], 0,0,0);
            acc[0][1] = __builtin_amdgcn_mfma_f32_16x16x32_bf16(a0, b1, acc[0][1], 0,0,0);
            acc[0][2] = __builtin_amdgcn_mfma_f32_16x16x32_bf16(a0, b2, acc[0][2], 0,0,0);
            acc[0][3] = __builtin_amdgcn_mfma_f32_16x16x32_bf16(a0, b3, acc[0][3], 0,0,0);
            acc[1][0] = __builtin_amdgcn_mfma_f32_16x16x32_bf16(a1, b0, acc[1][0], 0,0,0);
            acc[1][1] = __builtin_amdgcn_mfma_f32_16x16x32_bf16(a1, b1, acc[1][1], 0,0,0);
            acc[1][2] = __builtin_amdgcn_mfma_f32_16x16x32_bf16(a1, b2, acc[1][2], 0,0,0);
            acc[1][3] = __builtin_amdgcn_mfma_f32_16x16x32_bf16(a1, b3, acc[1][3], 0,0,0);
        }
    }

    // ---- epilogue: bias + relu; D layout col=lane&15, row=(lane>>4)*4+i ----
    #pragma unroll
    for (int mf = 0; mf < 2; ++mf)
    #pragma unroll
    for (int nf = 0; nf < 4; ++nf) {
        const int col = wn*64 + nf*16 + (lane & 15);
        const float bv = bias[col];
        #pragma unroll
        for (int i = 0; i < 4; ++i) {
            const int row = m0 + wm*32 + mf*16 + (lane >> 4)*4 + i;
            float v = fmaxf(acc[mf][nf][i] + bv, 0.0f);
            if (MODE == 1) outb[(size_t)row*BN + col] = __float2bfloat16(v);
            else           outf[(size_t)row*BN + col] = v;
        }
    }
}

// ---------------- K6: pos_skip + batch chunks ----------------
__global__ __launch_bounds__(256)
void tail_kernel(const float* __restrict__ pos_skip, float* __restrict__ out)
{
    int e = blockIdx.x*256 + threadIdx.x;
    if (e < NFINE*3) out[(size_t)NFINE*COUT + e] = pos_skip[e];
    if (e < NFINE)   out[(size_t)NFINE*COUT + (size_t)NFINE*3 + e] = (float)(e / NF);
}

extern "C" void kernel_launch(void* const* d_in, const int* in_sizes, int n_in,
                              void* d_out, int out_size, void* d_ws, size_t ws_size,
                              hipStream_t stream) {
    const float* x        = (const float*)d_in[0];
    const float* pos      = (const float*)d_in[1];
    const float* x_skip   = (const float*)d_in[4];
    const float* pos_skip = (const float*)d_in[5];
    const float* W1       = (const float*)d_in[8];
    const float* b1       = (const float*)d_in[9];
    const float* W2       = (const float*)d_in[10];
    const float* b2       = (const float*)d_in[11];
    float* out = (float*)d_out;
    char* ws = (char*)d_ws;

    // workspace layout (16B-aligned)
    int*            widx = (int*)  (ws + 0);                 //   786,432 B
    float*          wval = (float*)(ws + 786432);            //   786,432 B
    __hip_bfloat16* W1t  = (__hip_bfloat16*)(ws + 1572864);  //   196,608 B
    __hip_bfloat16* W2t  = (__hip_bfloat16*)(ws + 1769472);  //   131,072 B
    __hip_bfloat16* h1   = (__hip_bfloat16*)(ws + 1900544);  // 33,554,432 B

    hipLaunchKernelGGL(knn_kernel, dim3(NB*(NF/KNN_QPB)), dim3(256), 0, stream,
                       pos, pos_skip, widx, wval);
    hipLaunchKernelGGL(prep_weights, dim3((CMID*KH + COUT*CMID + 255)/256), dim3(256), 0, stream,
                       W1, W2, W1t, W2t);
    // GEMM1 fused with interpolation: h1 = relu([interp|x_skip] @ W1 + b1), bf16
    hipLaunchKernelGGL((gemm_fused<1, KH>), dim3(NFINE/BM), dim3(512), 0, stream,
                       x, x_skip, widx, wval, W1t, b1, h1, nullptr);
    // GEMM2: out = relu(h1 @ W2 + b2), f32
    hipLaunchKernelGGL((gemm_fused<0, CMID>), dim3(NFINE/BM), dim3(512), 0, stream,
                       h1, nullptr, nullptr, nullptr, W2t, b2, nullptr, out);
    hipLaunchKernelGGL(tail_kernel, dim3((NFINE*3 + 255)/256), dim3(256), 0, stream,
                       pos_skip, out);
}

// Round 4
// 96.964 us; speedup vs baseline: 2.4397x; 1.0943x over previous
//
#include <hip/hip_runtime.h>
#include <hip/hip_bf16.h>

// Problem constants (fixed by setup_inputs)
#define NB    16
#define NC    1024
#define NF    4096
#define NFINE (NB*NF)     // 65536
#define CIN   256
#define CSKIP 128
#define KH    (CIN+CSKIP) // 384
#define CMID  256
#define COUT  256

typedef __attribute__((ext_vector_type(8))) short short8;
typedef __attribute__((ext_vector_type(4))) float f32x4;
typedef __attribute__((ext_vector_type(4))) unsigned int u32x4;

// ---------------- K1: 3-NN, SoA LDS + b128 reads + branchless insert ----------------
#define KNN_G   8
#define KNN_QPB 32   // queries per 256-thread block

__global__ __launch_bounds__(256)
void knn_kernel(const float* __restrict__ pos,
                const float* __restrict__ pos_skip,
                int* __restrict__ widx,
                float* __restrict__ wval)
{
    __shared__ float spx[NC], spy[NC], spz[NC];
    const int blocks_per_cloud = NF/KNN_QPB;         // 128
    const int b  = blockIdx.x / blocks_per_cloud;
    const int qb = blockIdx.x % blocks_per_cloud;
    const float* pc = pos + (size_t)b*NC*3;
    for (int i = threadIdx.x; i < NC; i += 256) {
        spx[i] = pc[3*i+0]; spy[i] = pc[3*i+1]; spz[i] = pc[3*i+2];
    }
    __syncthreads();

    const int t  = threadIdx.x;
    const int g  = t & (KNN_G-1);
    const int ql = t >> 3;
    const int q  = b*NF + qb*KNN_QPB + ql;
    const float qx = pos_skip[(size_t)q*3+0];
    const float qy = pos_skip[(size_t)q*3+1];
    const float qz = pos_skip[(size_t)q*3+2];

    float d0 = 3.0e38f, dA = 3.0e38f, dB = 3.0e38f;
    int   i0 = 0,       iA = 0,       iB = 0;

    // branchless sorted insert of (d, j) into (d0<=dA<=dB)
    #define INS(d, j) do {                                        \
        bool c2 = (d) < dB, c1 = (d) < dA, c0 = (d) < d0;         \
        dB = c1 ? dA : (c2 ? (d) : dB);                           \
        iB = c1 ? iA : (c2 ? (j) : iB);                           \
        dA = c0 ? d0 : (c1 ? (d) : dA);                           \
        iA = c0 ? i0 : (c1 ? (j) : iA);                           \
        d0 = c0 ? (d) : d0;                                       \
        i0 = c0 ? (j) : i0;                                       \
    } while (0)

    #pragma unroll 2
    for (int it = 0; it < NC/32; ++it) {      // 32 iters, 4 candidates/lane each
        const int jb = it*32 + g*4;
        f32x4 px = *(const f32x4*)&spx[jb];
        f32x4 py = *(const f32x4*)&spy[jb];
        f32x4 pz = *(const f32x4*)&spz[jb];
        #pragma unroll
        for (int u = 0; u < 4; ++u) {
            float dx = qx - px[u];
            float dy = qy - py[u];
            float dz = qz - pz[u];
            float d = dx*dx + dy*dy + dz*dz;
            INS(d, jb + u);
        }
    }

    // merge sorted triples across the 8-lane group
    #pragma unroll
    for (int m = 1; m < KNN_G; m <<= 1) {
        float e0 = __shfl_xor(d0, m), e1 = __shfl_xor(dA, m), e2 = __shfl_xor(dB, m);
        int   f0 = __shfl_xor(i0, m), f1 = __shfl_xor(iA, m), f2 = __shfl_xor(iB, m);
        INS(e0, f0); INS(e1, f1); INS(e2, f2);
    }
    #undef INS

    if (g == 0) {
        float w0 = 1.0f / fmaxf(d0, 1e-16f);
        float w1 = 1.0f / fmaxf(dA, 1e-16f);
        float w2 = 1.0f / fmaxf(dB, 1e-16f);
        float inv = 1.0f / (w0 + w1 + w2);
        widx[q*3+0] = b*NC + i0;  wval[q*3+0] = w0*inv;
        widx[q*3+1] = b*NC + iA;  wval[q*3+1] = w1*inv;
        widx[q*3+2] = b*NC + iB;  wval[q*3+2] = w2*inv;
    }
}

// ---------------- K2: weights -> bf16, transposed [N][K] ----------------
__global__ __launch_bounds__(256)
void prep_weights(const float* __restrict__ W1, const float* __restrict__ W2,
                  __hip_bfloat16* __restrict__ W1t, __hip_bfloat16* __restrict__ W2t)
{
    int e = blockIdx.x*256 + threadIdx.x;
    if (e < CMID*KH) {
        int n = e / KH, k = e % KH;
        W1t[e] = __float2bfloat16(W1[(size_t)k*CMID + n]);
    }
    int e2 = e - CMID*KH;
    if (e2 >= 0 && e2 < COUT*CMID) {
        int n = e2 / CMID, k = e2 % CMID;
        W2t[e2] = __float2bfloat16(W2[(size_t)k*COUT + n]);
    }
}

// ---------------- fused GEMM: tile 128x256, 8 waves of 64x64, BK=64 ----------------
// LDS chunk layout: row r, 16B chunk c stored at col ((c ^ (r&7))*8)  -> <=2-way conflicts
// Pipeline: [b1; regs->LDS; b2; issue loads(s+1); MFMA] so load latency hides under MFMA.
#define BMm  128
#define BNn  256
#define BKk  64

template<int MODE, int KTOT>   // MODE1: A = interp(x)|x_skip (fp32 sources); MODE0: A = bf16
__global__ __launch_bounds__(512, 2)
void gemm_fused(const void* __restrict__ Asrc,
                const float* __restrict__ x_skip,
                const int* __restrict__ widx,
                const float* __restrict__ wval,
                const __hip_bfloat16* __restrict__ Bt,   // [BNn][KTOT]
                const float* __restrict__ bias,
                __hip_bfloat16* __restrict__ outb,
                float* __restrict__ outf)
{
    __shared__ __align__(16) short As[BMm][BKk];
    __shared__ __align__(16) short Bs[BNn][BKk];
    constexpr int NSTEP = KTOT / BKk;

    // XCD-chunked bijective tile swizzle (gridDim.x % 8 == 0)
    const int nwg = gridDim.x;
    const int tile = (blockIdx.x & 7) * (nwg >> 3) + (blockIdx.x >> 3);
    const int m0 = tile * BMm;

    const int t = threadIdx.x;
    const int wave = t >> 6, lane = t & 63;
    const int wm = wave >> 2, wn = wave & 3;      // 2x4 wave grid, 64x64 per wave
    const int rl = lane & 15, kq = lane >> 4;
    const short* Br = (const short*)Bt;

    // A staging slot: row ar (0..127), chunks acb and acb+4 (cols acb*8, acb*8+32)
    const int ar  = t >> 2;
    const int acb = t & 3;

    int j0=0, j1=0, j2=0; float w0=0.f, w1=0.f, w2=0.f;
    if (MODE == 1) {
        const int gr = m0 + ar;
        j0 = widx[gr*3+0]; j1 = widx[gr*3+1]; j2 = widx[gr*3+2];
        w0 = wval[gr*3+0]; w1 = wval[gr*3+1]; w2 = wval[gr*3+2];
    }

    f32x4 rA[12];      // MODE1 gather: 2 chunks x 3 nbr x 2 f32x4; MODE0: rA[0..1] raw bf16
    u32x4 rB[4];

    #define LOADB(K0) do {                                                     \
        _Pragma("unroll")                                                      \
        for (int i = 0; i < 4; ++i) {                                          \
            const int ch = t + i*512;                                          \
            const int rr = ch >> 3, cc = ch & 7;                               \
            rB[i] = *(const u32x4*)&Br[(size_t)rr*KTOT + (K0) + cc*8];         \
        }                                                                      \
    } while (0)

    #define LOADA(K0) do {                                                     \
        if (MODE == 0) {                                                       \
            const short* Ar = (const short*)Asrc;                              \
            const short* p = &Ar[(size_t)(m0+ar)*KTOT + (K0) + acb*8];         \
            rA[0] = *(const f32x4*)p;                                          \
            rA[1] = *(const f32x4*)(p+32);                                     \
        } else if ((K0) < CIN) {                                               \
            const float* xp = (const float*)Asrc;                              \
            _Pragma("unroll")                                                  \
            for (int h = 0; h < 2; ++h) {                                      \
                const int k = (K0) + acb*8 + h*32;                             \
                const float* p0 = &xp[(size_t)j0*CIN + k];                     \
                const float* p1 = &xp[(size_t)j1*CIN + k];                     \
                const float* p2 = &xp[(size_t)j2*CIN + k];                     \
                rA[h*6+0] = *(const f32x4*)p0; rA[h*6+1] = *(const f32x4*)(p0+4); \
                rA[h*6+2] = *(const f32x4*)p1; rA[h*6+3] = *(const f32x4*)(p1+4); \
                rA[h*6+4] = *(const f32x4*)p2; rA[h*6+5] = *(const f32x4*)(p2+4); \
            }                                                                  \
        } else {                                                               \
            _Pragma("unroll")                                                  \
            for (int h = 0; h < 2; ++h) {                                      \
                const int k = (K0) + acb*8 + h*32 - CIN;                       \
                const float* sp = &x_skip[(size_t)(m0+ar)*CSKIP + k];          \
                rA[h*2+0] = *(const f32x4*)sp; rA[h*2+1] = *(const f32x4*)(sp+4); \
            }                                                                  \
        }                                                                      \
    } while (0)

    f32x4 acc[4][4] = {};   // 64 VGPR accumulator, wave tile 64x64

    LOADA(0); LOADB(0);

    #pragma unroll
    for (int s = 0; s < NSTEP; ++s) {
        const int k0 = s * BKk;
        __syncthreads();   // prev-step LDS reads complete; drains our step-s loads (needed now)
        // ---- regs -> LDS (swizzled chunks) ----
        if (MODE == 0) {
            *(u32x4*)&As[ar][((acb  ) ^ (ar&7))*8] = *(u32x4*)&rA[0];
            *(u32x4*)&As[ar][((acb+4) ^ (ar&7))*8] = *(u32x4*)&rA[1];
        } else if (k0 < CIN) {
            #pragma unroll
            for (int h = 0; h < 2; ++h) {
                short8 sv;
                #pragma unroll
                for (int u = 0; u < 2; ++u) {
                    f32x4 a = rA[h*6+u], bq = rA[h*6+2+u], c = rA[h*6+4+u];
                    #pragma unroll
                    for (int e = 0; e < 4; ++e) {
                        float v = w0*a[e] + w1*bq[e] + w2*c[e];
                        __hip_bfloat16 bb = __float2bfloat16(v);
                        ((short*)&sv)[u*4+e] = *(short*)&bb;
                    }
                }
                *(short8*)&As[ar][((acb + h*4) ^ (ar&7))*8] = sv;
            }
        } else {
            #pragma unroll
            for (int h = 0; h < 2; ++h) {
                short8 sv;
                #pragma unroll
                for (int u = 0; u < 2; ++u) {
                    f32x4 a = rA[h*2+u];
                    #pragma unroll
                    for (int e = 0; e < 4; ++e) {
                        __hip_bfloat16 bb = __float2bfloat16(a[e]);
                        ((short*)&sv)[u*4+e] = *(short*)&bb;
                    }
                }
                *(short8*)&As[ar][((acb + h*4) ^ (ar&7))*8] = sv;
            }
        }
        #pragma unroll
        for (int i = 0; i < 4; ++i) {
            const int ch = t + i*512;
            const int rr = ch >> 3, cc = ch & 7;
            *(u32x4*)&Bs[rr][(cc ^ (rr&7))*8] = rB[i];
        }
        __syncthreads();   // LDS ready
        // ---- issue next-step global loads NOW; MFMA phase covers their latency ----
        if (s + 1 < NSTEP) { LOADA(k0 + BKk); LOADB(k0 + BKk); }
        // ---- MFMA: 2 k-halves x (4+4 reads, 16 mfma) ----
        #pragma unroll
        for (int kh = 0; kh < 2; ++kh) {
            const int kc = kh*4 + kq;
            short8 af[4], bf[4];
            #pragma unroll
            for (int mf = 0; mf < 4; ++mf)
                af[mf] = *(const short8*)&As[wm*64 + mf*16 + rl][(kc ^ (rl&7))*8];
            #pragma unroll
            for (int nf = 0; nf < 4; ++nf)
                bf[nf] = *(const short8*)&Bs[wn*64 + nf*16 + rl][(kc ^ (rl&7))*8];
            #pragma unroll
            for (int mf = 0; mf < 4; ++mf)
            #pragma unroll
            for (int nf = 0; nf < 4; ++nf)
                acc[mf][nf] = __builtin_amdgcn_mfma_f32_16x16x32_bf16(af[mf], bf[nf], acc[mf][nf], 0,0,0);
        }
    }
    #undef LOADA
    #undef LOADB

    // ---- epilogue: bias + relu; D layout col=lane&15, row=(lane>>4)*4+i ----
    #pragma unroll
    for (int mf = 0; mf < 4; ++mf)
    #pragma unroll
    for (int nf = 0; nf < 4; ++nf) {
        const int col = wn*64 + nf*16 + rl;
        const float bv = bias[col];
        #pragma unroll
        for (int i = 0; i < 4; ++i) {
            const int row = m0 + wm*64 + mf*16 + kq*4 + i;
            float v = fmaxf(acc[mf][nf][i] + bv, 0.0f);
            if (MODE == 1) outb[(size_t)row*BNn + col] = __float2bfloat16(v);
            else           outf[(size_t)row*BNn + col] = v;
        }
    }
}

// ---------------- K6: pos_skip + batch chunks ----------------
__global__ __launch_bounds__(256)
void tail_kernel(const float* __restrict__ pos_skip, float* __restrict__ out)
{
    int e = blockIdx.x*256 + threadIdx.x;
    if (e < NFINE*3) out[(size_t)NFINE*COUT + e] = pos_skip[e];
    if (e < NFINE)   out[(size_t)NFINE*COUT + (size_t)NFINE*3 + e] = (float)(e / NF);
}

extern "C" void kernel_launch(void* const* d_in, const int* in_sizes, int n_in,
                              void* d_out, int out_size, void* d_ws, size_t ws_size,
                              hipStream_t stream) {
    const float* x        = (const float*)d_in[0];
    const float* pos      = (const float*)d_in[1];
    const float* x_skip   = (const float*)d_in[4];
    const float* pos_skip = (const float*)d_in[5];
    const float* W1       = (const float*)d_in[8];
    const float* b1       = (const float*)d_in[9];
    const float* W2       = (const float*)d_in[10];
    const float* b2       = (const float*)d_in[11];
    float* out = (float*)d_out;
    char* ws = (char*)d_ws;

    int*            widx = (int*)  (ws + 0);
    float*          wval = (float*)(ws + 786432);
    __hip_bfloat16* W1t  = (__hip_bfloat16*)(ws + 1572864);
    __hip_bfloat16* W2t  = (__hip_bfloat16*)(ws + 1769472);
    __hip_bfloat16* h1   = (__hip_bfloat16*)(ws + 1900544);  // 33,554,432 B

    hipLaunchKernelGGL(knn_kernel, dim3(NB*(NF/KNN_QPB)), dim3(256), 0, stream,
                       pos, pos_skip, widx, wval);
    hipLaunchKernelGGL(prep_weights, dim3((CMID*KH + COUT*CMID + 255)/256), dim3(256), 0, stream,
                       W1, W2, W1t, W2t);
    hipLaunchKernelGGL((gemm_fused<1, KH>), dim3(NFINE/BMm), dim3(512), 0, stream,
                       x, x_skip, widx, wval, W1t, b1, h1, nullptr);
    hipLaunchKernelGGL((gemm_fused<0, CMID>), dim3(NFINE/BMm), dim3(512), 0, stream,
                       h1, nullptr, nullptr, nullptr, W2t, b2, nullptr, out);
    hipLaunchKernelGGL(tail_kernel, dim3((NFINE*3 + 255)/256), dim3(256), 0, stream,
                       pos_skip, out);
}